// Round 9
// baseline (261.919 us; speedup 1.0000x reference)
//
#include <hip/hip_runtime.h>

#define LRELU(a) ((a) > 0.f ? (a) : 0.2f * (a))

// ---------- block-wide inclusive scan helper (256 threads, 4 waves) ----------
__device__ __forceinline__ int blockScanIncl256(int v, int* wl) {
  int t = threadIdx.x, lane = t & 63, w = t >> 6;
  int x = v;
#pragma unroll
  for (int o = 1; o < 64; o <<= 1) {
    int tmp = __shfl_up(x, (unsigned)o, 64);
    if (lane >= o) x += tmp;
  }
  if (lane == 63) wl[w] = x;
  __syncthreads();
  if (t == 0) {
    int s = 0;
#pragma unroll
    for (int j = 0; j < 4; ++j) { int tv = wl[j]; wl[j] = s; s += tv; }
  }
  __syncthreads();
  return x + wl[w];
}

// ---------- CSR build ----------
__global__ __launch_bounds__(256) void k_deg(const int* __restrict__ dst,
                                             int* __restrict__ deg, int E) {
  int e = blockIdx.x * 256 + threadIdx.x;
  if (e < E) atomicAdd(&deg[dst[e]], 1);
}

__global__ __launch_bounds__(256) void k_chunksum(const int* __restrict__ deg,
                                                  int* __restrict__ bsum, int n) {
  __shared__ int wl[4];
  int i = blockIdx.x * 256 + threadIdx.x;
  int v = (i < n) ? deg[i] : 0;
#pragma unroll
  for (int o = 1; o < 64; o <<= 1) v += __shfl_xor(v, o, 64);
  int lane = threadIdx.x & 63, w = threadIdx.x >> 6;
  if (lane == 0) wl[w] = v;
  __syncthreads();
  if (threadIdx.x == 0) bsum[blockIdx.x] = wl[0] + wl[1] + wl[2] + wl[3];
}

// single block; requires nb <= 256 (N <= 65536)
__global__ __launch_bounds__(256) void k_bscan(int* __restrict__ bsum, int nb,
                                               int* __restrict__ csr_off, int n) {
  __shared__ int wl[4];
  int t = threadIdx.x;
  int v = (t < nb) ? bsum[t] : 0;
  int incl = blockScanIncl256(v, wl);
  if (t < nb) bsum[t] = incl - v;  // exclusive block offsets
  if (t == 255) csr_off[n] = incl; // grand total
}

__global__ __launch_bounds__(256) void k_chunkscan(const int* __restrict__ deg,
                                                   const int* __restrict__ bsum,
                                                   int* __restrict__ csr_off,
                                                   int* __restrict__ fill, int n) {
  __shared__ int wl[4];
  int i = blockIdx.x * 256 + threadIdx.x;
  int v = (i < n) ? deg[i] : 0;
  int incl = blockScanIncl256(v, wl);
  int o = bsum[blockIdx.x] + incl - v;
  if (i < n) { csr_off[i] = o; fill[i] = o; }
}

// ---------- chunked-K tiled f32 GEMM body + fused attention-logit epilogue ----
// H[b0:b0+64][0:64] = X[b0:b0+64][0:K] @ W[K][64]; als/ald = h . a per head.
// 256 threads = 16x16, each computes a 4x4 tile. LDS ~17.5KB -> 8 blocks/CU.
template <int K, int HH>
__device__ __forceinline__ void gemm_body(const float* __restrict__ X,
                                          const float* __restrict__ W,
                                          const float* __restrict__ a_s,
                                          const float* __restrict__ a_d,
                                          float* __restrict__ H,
                                          float* __restrict__ als,
                                          float* __restrict__ ald,
                                          int n, int bid) {
  constexpr int KC = 32;
  __shared__ float Xs[64][KC + 4];   // 9216 B
  __shared__ float Ws[KC][64 + 4];   // 8704 B
  int t = threadIdx.x;
  int b0 = bid * 64;
  int tx = t & 15, ty = t >> 4;
  float acc[4][4] = {};
  for (int kc = 0; kc < K; kc += KC) {
    if (kc) __syncthreads();
    {
      int i = t * 8;
      int node = i >> 5, k = i & 31;
      int r = b0 + node;
      float4 v0 = make_float4(0.f, 0.f, 0.f, 0.f), v1 = v0;
      if (r < n) {
        const float* src = X + (size_t)r * K + kc + k;
        v0 = *(const float4*)src;
        v1 = *(const float4*)(src + 4);
      }
      *(float4*)&Xs[node][k] = v0;
      *(float4*)&Xs[node][k + 4] = v1;
    }
    {
      int i = t * 8;
      int kk = i >> 6, c = i & 63;
      const float* src = W + (size_t)(kc + kk) * 64 + c;
      *(float4*)&Ws[kk][c] = *(const float4*)src;
      *(float4*)&Ws[kk][c + 4] = *(const float4*)(src + 4);
    }
    __syncthreads();
#pragma unroll
    for (int k4 = 0; k4 < KC; k4 += 4) {
      float wvf[4][4];
#pragma unroll
      for (int j = 0; j < 4; ++j)
        *(float4*)&wvf[j][0] = *(const float4*)&Ws[k4 + j][tx * 4];
#pragma unroll
      for (int i = 0; i < 4; ++i) {
        float xvf[4];
        *(float4*)&xvf[0] = *(const float4*)&Xs[ty * 4 + i][k4];
#pragma unroll
        for (int kk = 0; kk < 4; ++kk)
#pragma unroll
          for (int j = 0; j < 4; ++j)
            acc[i][j] = fmaf(xvf[kk], wvf[kk][j], acc[i][j]);
      }
    }
  }
#pragma unroll
  for (int i = 0; i < 4; ++i) {
    int node = b0 + ty * 4 + i;
    if (node < n)
      *(float4*)&H[(size_t)node * 64 + tx * 4] =
          make_float4(acc[i][0], acc[i][1], acc[i][2], acc[i][3]);
  }
  // ---- fused attention logits: als/ald[node*HH+head] ----
  constexpr int C = 64 / HH;     // channels per head
  constexpr int GL = C / 4;      // tx lanes per head group
  float asv[4], adv[4];
#pragma unroll
  for (int j = 0; j < 4; ++j) { asv[j] = a_s[tx * 4 + j]; adv[j] = a_d[tx * 4 + j]; }
#pragma unroll
  for (int i = 0; i < 4; ++i) {
    float ps = 0.f, pd = 0.f;
#pragma unroll
    for (int j = 0; j < 4; ++j) {
      ps = fmaf(acc[i][j], asv[j], ps);
      pd = fmaf(acc[i][j], adv[j], pd);
    }
#pragma unroll
    for (int o = 1; o < GL; o <<= 1) {
      ps += __shfl_xor(ps, o, 64);
      pd += __shfl_xor(pd, o, 64);
    }
    int node = b0 + ty * 4 + i;
    if (node < n && (tx & (GL - 1)) == 0) {
      int head = tx / GL;
      als[(size_t)node * HH + head] = ps;
      ald[(size_t)node * HH + head] = pd;
    }
  }
}

// ---------- fused: gemm1 (blocks < gemmBlocks) || scatter+edge-dots (the rest) ----
// scatter: edge-ordered coalesced edge_attr read, dots vs (We1@ae1),(We2@ae2),
// ONE 32B scattered struct per edge: epk[p*8] = {d0,d1,d2,d3,q,src,-,-}.
__global__ __launch_bounds__(256) void k_gs(const float* __restrict__ X,
                                            const float* __restrict__ W,
                                            const float* __restrict__ a_s,
                                            const float* __restrict__ a_d,
                                            float* __restrict__ H,
                                            float* __restrict__ als,
                                            float* __restrict__ ald, int n,
                                            int gemmBlocks,
                                            const int* __restrict__ dst,
                                            const int* __restrict__ src,
                                            const float* __restrict__ edge_attr,
                                            const float* __restrict__ We1,
                                            const float* __restrict__ ae1,
                                            const float* __restrict__ We2,
                                            const float* __restrict__ ae2,
                                            int* __restrict__ fill,
                                            float* __restrict__ epk, int E) {
  if ((int)blockIdx.x < gemmBlocks) {
    gemm_body<128, 4>(X, W, a_s, a_d, H, als, ald, n, blockIdx.x);
  } else {
    __shared__ float wa1s[64];  // [k*4+h]
    __shared__ float wa2s[16];
    int t = threadIdx.x;
    if (t < 64) {
      int k = t >> 2, hh = t & 3;
      float s = 0.f;
#pragma unroll
      for (int c = 0; c < 16; ++c)
        s = fmaf(We1[k * 64 + hh * 16 + c], ae1[hh * 16 + c], s);
      wa1s[t] = s;
    } else if (t < 80) {
      int k = t - 64;
      float s = 0.f;
#pragma unroll
      for (int c = 0; c < 64; ++c) s = fmaf(We2[k * 64 + c], ae2[c], s);
      wa2s[k] = s;
    }
    __syncthreads();
    int base = (blockIdx.x - gemmBlocks) * 1024 + t;
#pragma unroll
    for (int r = 0; r < 4; ++r) {
      int e = base + r * 256;
      if (e < E) {
        int d = dst[e], s = src[e];
        const float4* ea = (const float4*)(edge_attr + (size_t)e * 16);
        float ev[16];
        *(float4*)&ev[0]  = ea[0];
        *(float4*)&ev[4]  = ea[1];
        *(float4*)&ev[8]  = ea[2];
        *(float4*)&ev[12] = ea[3];
        float d0 = 0.f, d1 = 0.f, d2 = 0.f, d3 = 0.f, q = 0.f;
#pragma unroll
        for (int k = 0; k < 16; ++k) {
          float4 w1 = *(const float4*)&wa1s[k * 4];
          d0 = fmaf(ev[k], w1.x, d0);
          d1 = fmaf(ev[k], w1.y, d1);
          d2 = fmaf(ev[k], w1.z, d2);
          d3 = fmaf(ev[k], w1.w, d3);
          q  = fmaf(ev[k], wa2s[k], q);
        }
        int p = atomicAdd(&fill[d], 1);
        float* o = epk + (size_t)p * 8;
        *(float4*)o = make_float4(d0, d1, d2, d3);
        *(float4*)(o + 4) = make_float4(q, __int_as_float(s), 0.f, 0.f);
      }
    }
  }
}

// ---------- layer 1 aggregation + FUSED layer-2 linear ----------
// phase 1: online softmax + Σd,Σq -> self-loop + loopdot2
// phase 2: batched (8-deep, double-buffered) h gathers, logits recomputed inline
// epilogue: out1 (register-only) -> h2 = out1@W2 via shfl-broadcast; als2/ald2.
__global__ __launch_bounds__(256) void k_agg1(const int* __restrict__ csr_off,
                                              const float* __restrict__ epk,
                                              const float* __restrict__ als1,
                                              const float* __restrict__ ald1,
                                              const float* __restrict__ h1,
                                              const float* __restrict__ b1,
                                              const float* __restrict__ W2,
                                              const float* __restrict__ as2,
                                              const float* __restrict__ ad2,
                                              float* __restrict__ h2,
                                              float* __restrict__ als2,
                                              float* __restrict__ ald2,
                                              float* __restrict__ loopdot2, int n) {
  int t = threadIdx.x, w = t >> 6, lane = t & 63;
  int node = blockIdx.x * 4 + w;
  if (node >= n) return;
  int s0 = csr_off[node], s1 = csr_off[node + 1];
  int nit = s1 - s0;
  int laneB = lane >> 2, laneH = lane & 3;
  float adv = ald1[(size_t)node * 4 + laneH];
  // ---- phase 1: online m/den + sums ----
  float m = -3e38f, den = 0.f, sumd = 0.f, sumq = 0.f;
  for (int i = s0 + laneB; i < s1; i += 16) {
    float d = epk[(size_t)i * 8 + laneH];
    int s = __float_as_int(epk[(size_t)i * 8 + 5]);
    float q = epk[(size_t)i * 8 + 4];
    float a = als1[(size_t)s * 4 + laneH] + adv + d;
    a = LRELU(a);
    float nm = fmaxf(m, a);
    den = den * __expf(m - nm) + __expf(a - nm);
    m = nm;
    sumd += d;
    if (laneH == 0) sumq += q;
  }
#pragma unroll
  for (int o = 4; o < 64; o <<= 1) {
    float om = __shfl_xor(m, o, 64);
    float od = __shfl_xor(den, o, 64);
    float nm = fmaxf(m, om);
    den = den * __expf(m - nm) + od * __expf(om - nm);
    m = nm;
    sumd += __shfl_xor(sumd, o, 64);
    sumq += __shfl_xor(sumq, o, 64);
  }
  float cd = fmaxf((float)nit, 1.f);
  float sl = als1[(size_t)node * 4 + laneH] + adv + sumd / cd;
  sl = LRELU(sl);
  {
    float nm = fmaxf(m, sl);
    den = den * __expf(m - nm) + __expf(sl - nm);
    m = nm;
  }
  if (lane == 0) loopdot2[node] = sumq / cd;
  int head = lane >> 4;  // head in channel layout
  float m_ch = __shfl(m, head, 64);
  float rd_ch = 1.f / __shfl(den, head, 64);
  float sl_ch = __shfl(sl, head, 64);
  float acc = __expf(sl_ch - m_ch) * h1[(size_t)node * 64 + lane];
  // ---- phase 2 ----
  if (nit > 0) {
    int nb = (nit + 7) >> 3;
    int laneE = lane & 7, laneB8 = (lane >> 2) & 7;
    int sv; float ev;
    float bufA[8], bufB[8];
    {
      int i1 = min(s0 + laneE, s1 - 1);
      sv = __float_as_int(epk[(size_t)i1 * 8 + 5]);
      int i2 = min(s0 + laneB8, s1 - 1);
      float d = epk[(size_t)i2 * 8 + laneH];
      int se = __float_as_int(epk[(size_t)i2 * 8 + 5]);
      ev = als1[(size_t)se * 4 + laneH] + adv + d;
      ev = LRELU(ev);
    }
#pragma unroll
    for (int j = 0; j < 8; ++j)
      bufA[j] = h1[(size_t)__shfl(sv, j, 64) * 64 + lane];
    for (int b = 0; b < nb; ++b) {
      int svN = 0; float evN = 0.f;
      bool pf = (b + 1 < nb);
      if (pf) {
        int base = s0 + (b + 1) * 8;
        int i1 = min(base + laneE, s1 - 1);
        svN = __float_as_int(epk[(size_t)i1 * 8 + 5]);
        int i2 = min(base + laneB8, s1 - 1);
        float d = epk[(size_t)i2 * 8 + laneH];
        int se = __float_as_int(epk[(size_t)i2 * 8 + 5]);
        evN = als1[(size_t)se * 4 + laneH] + adv + d;
        evN = LRELU(evN);
#pragma unroll
        for (int j = 0; j < 8; ++j)
          bufB[j] = h1[(size_t)__shfl(svN, j, 64) * 64 + lane];
      }
      int rem = nit - b * 8;
#pragma unroll
      for (int j = 0; j < 8; ++j) {
        float aj = __shfl(ev, j * 4 + head, 64);
        float ex = (j < rem) ? __expf(aj - m_ch) : 0.f;
        acc = fmaf(ex, bufA[j], acc);
      }
      if (pf) {
#pragma unroll
        for (int j = 0; j < 8; ++j) bufA[j] = bufB[j];
        sv = svN; ev = evN;
      }
    }
  }
  float r = acc * rd_ch + b1[lane];
  r = r > 0.f ? r : expm1f(r);  // out1 value, register-only (ELU fused)
  // ---- fused layer-2 linear: h2[node][lane] = sum_k out1[k] * W2[k][lane] ----
  float a0 = 0.f, a1 = 0.f, a2 = 0.f, a3 = 0.f;
#pragma unroll
  for (int k = 0; k < 64; k += 4) {
    float r0 = __shfl(r, k, 64);
    float r1 = __shfl(r, k + 1, 64);
    float r2 = __shfl(r, k + 2, 64);
    float r3 = __shfl(r, k + 3, 64);
    a0 = fmaf(r0, W2[(k + 0) * 64 + lane], a0);
    a1 = fmaf(r1, W2[(k + 1) * 64 + lane], a1);
    a2 = fmaf(r2, W2[(k + 2) * 64 + lane], a2);
    a3 = fmaf(r3, W2[(k + 3) * 64 + lane], a3);
  }
  float h2v = (a0 + a1) + (a2 + a3);
  h2[(size_t)node * 64 + lane] = h2v;
  float ps = h2v * as2[lane], pd = h2v * ad2[lane];
#pragma unroll
  for (int o = 1; o < 64; o <<= 1) {
    ps += __shfl_xor(ps, o, 64);
    pd += __shfl_xor(pd, o, 64);
  }
  if (lane == 0) { als2[node] = ps; ald2[node] = pd; }
}

// ---------- layer 2 aggregation (scalar head): logits from epk.q + als2 ----------
__global__ __launch_bounds__(256) void k_agg2(const int* __restrict__ csr_off,
                                              const float* __restrict__ epk,
                                              const float* __restrict__ als2,
                                              const float* __restrict__ ald2,
                                              const float* __restrict__ loopdot2,
                                              const float* __restrict__ h2,
                                              const float* __restrict__ b2,
                                              float* __restrict__ out2, int n) {
  int t = threadIdx.x, w = t >> 6, lane = t & 63;
  int node = blockIdx.x * 4 + w;
  if (node >= n) return;
  int s0 = csr_off[node], s1 = csr_off[node + 1];
  int nit = s1 - s0;
  float adv = ald2[node];
  // ---- phase 1: online m/den ----
  float m = -3e38f, den = 0.f;
  for (int i = s0 + lane; i < s1; i += 64) {
    float2 qs = *(const float2*)(epk + (size_t)i * 8 + 4);
    int s = __float_as_int(qs.y);
    float a = als2[s] + adv + qs.x;
    a = LRELU(a);
    float nm = fmaxf(m, a);
    den = den * __expf(m - nm) + __expf(a - nm);
    m = nm;
  }
#pragma unroll
  for (int o = 1; o < 64; o <<= 1) {
    float om = __shfl_xor(m, o, 64);
    float od = __shfl_xor(den, o, 64);
    float nm = fmaxf(m, om);
    den = den * __expf(m - nm) + od * __expf(om - nm);
    m = nm;
  }
  float sl = als2[node] + adv + loopdot2[node];
  sl = LRELU(sl);
  {
    float nm = fmaxf(m, sl);
    den = den * __expf(m - nm) + __expf(sl - nm);
    m = nm;
  }
  float rd = 1.f / den;
  float acc = __expf(sl - m) * h2[(size_t)node * 64 + lane];
  // ---- phase 2 ----
  if (nit > 0) {
    int nb = (nit + 7) >> 3;
    int laneE = lane & 7;
    int sv; float ev;
    {
      int i1 = min(s0 + laneE, s1 - 1);
      float2 qs = *(const float2*)(epk + (size_t)i1 * 8 + 4);
      sv = __float_as_int(qs.y);
      ev = LRELU(als2[sv] + adv + qs.x);
    }
    float bufA[8], bufB[8];
#pragma unroll
    for (int j = 0; j < 8; ++j)
      bufA[j] = h2[(size_t)__shfl(sv, j, 64) * 64 + lane];
    for (int b = 0; b < nb; ++b) {
      int svN = 0; float evN = 0.f;
      bool pf = (b + 1 < nb);
      if (pf) {
        int i1 = min(s0 + (b + 1) * 8 + laneE, s1 - 1);
        float2 qs = *(const float2*)(epk + (size_t)i1 * 8 + 4);
        svN = __float_as_int(qs.y);
        evN = LRELU(als2[svN] + adv + qs.x);
#pragma unroll
        for (int j = 0; j < 8; ++j)
          bufB[j] = h2[(size_t)__shfl(svN, j, 64) * 64 + lane];
      }
      int rem = nit - b * 8;
#pragma unroll
      for (int j = 0; j < 8; ++j) {
        float aj = __shfl(ev, j, 64);
        float ex = (j < rem) ? __expf(aj - m) : 0.f;
        acc = fmaf(ex, bufA[j], acc);
      }
      if (pf) {
#pragma unroll
        for (int j = 0; j < 8; ++j) bufA[j] = bufB[j];
        sv = svN; ev = evN;
      }
    }
  }
  out2[(size_t)node * 64 + lane] = acc * rd + b2[lane];  // H2=1: mean = identity
}

// ---------- pooling: sorted batch, wave handles 64 consecutive nodes ----------
__global__ __launch_bounds__(256) void k_pool(const float* __restrict__ out2,
                                              const int* __restrict__ batch,
                                              float* __restrict__ pooled,
                                              float* __restrict__ cnt, int n) {
  int wgl = blockIdx.x * 4 + (threadIdx.x >> 6);
  int lane = threadIdx.x & 63;
  int i0 = wgl * 64;
  if (i0 >= n) return;
  int i1 = min(i0 + 64, n);
  int cur = -1;
  float acc = 0.f, c = 0.f;
  for (int i = i0; i < i1; ++i) {
    int g = batch[i];
    if (g != cur) {
      if (cur >= 0) {
        atomicAdd(&pooled[cur * 64 + lane], acc);
        if (lane == 0) atomicAdd(&cnt[cur], c);
      }
      cur = g; acc = 0.f; c = 0.f;
    }
    acc += out2[(size_t)i * 64 + lane];
    c += 1.f;
  }
  if (cur >= 0) {
    atomicAdd(&pooled[cur * 64 + lane], acc);
    if (lane == 0) atomicAdd(&cnt[cur], c);
  }
}

// ---------- final: out[g,:] = (pooled[g,:]/cnt[g]) @ Pw + Pb ----------
__global__ __launch_bounds__(64) void k_final(const float* __restrict__ pooled,
                                              const float* __restrict__ cnt,
                                              const float* __restrict__ Pw,
                                              const float* __restrict__ Pb,
                                              float* __restrict__ out) {
  __shared__ float m[64];
  int g = blockIdx.x, o = threadIdx.x;
  m[o] = pooled[g * 64 + o] / fmaxf(cnt[g], 1.f);
  __syncthreads();
  float s = Pb[o];
#pragma unroll
  for (int c = 0; c < 64; ++c) s = fmaf(m[c], Pw[c * 64 + o], s);
  out[g * 64 + o] = s;
}

extern "C" void kernel_launch(void* const* d_in, const int* in_sizes, int n_in,
                              void* d_out, int out_size, void* d_ws, size_t ws_size,
                              hipStream_t stream) {
  const float* x         = (const float*)d_in[0];
  const int*   edge_index= (const int*)d_in[1];
  const float* edge_attr = (const float*)d_in[2];
  const int*   batch     = (const int*)d_in[3];
  const float* W1  = (const float*)d_in[4];
  const float* as1 = (const float*)d_in[5];
  const float* ad1 = (const float*)d_in[6];
  const float* We1 = (const float*)d_in[7];
  const float* ae1 = (const float*)d_in[8];
  const float* b1  = (const float*)d_in[9];
  const float* W2  = (const float*)d_in[10];
  const float* as2 = (const float*)d_in[11];
  const float* ad2 = (const float*)d_in[12];
  const float* We2 = (const float*)d_in[13];
  const float* ae2 = (const float*)d_in[14];
  const float* b2  = (const float*)d_in[15];
  const float* Pw  = (const float*)d_in[16];
  const float* Pb  = (const float*)d_in[17];

  const int N = in_sizes[0] / 128;
  const int E = in_sizes[1] / 2;
  const int G = out_size / 64;
  const int* srcI = edge_index;
  const int* dstI = edge_index + E;

  // ---- workspace layout (32B-aligned slots) ----
  float* ws = (float*)d_ws;
  size_t off = 0;
  auto alloc = [&](size_t elems) {
    float* p = ws + off;
    off += (elems + 7) & ~(size_t)7;
    return p;
  };
  int*   deg       = (int*)alloc(N);            // zeroed
  float* cnt       = alloc(G);                  // zeroed
  float* pooled    = alloc((size_t)G * 64);     // zeroed
  size_t zero_bytes = off * sizeof(float);
  int*   csr_off   = (int*)alloc(N + 1);
  int*   fill      = (int*)alloc(N);
  int*   bsum      = (int*)alloc(1024);
  float* epk       = alloc((size_t)E * 8);      // {d0,d1,d2,d3,q,src,-,-}/CSR slot
  float* loopdot2  = alloc((size_t)N);
  float* h         = alloc((size_t)N * 64);     // h1; reused as out2 after agg1
  float* als       = alloc((size_t)N * 4);      // layer-1
  float* ald       = alloc((size_t)N * 4);
  float* h2buf     = alloc((size_t)N * 64);     // h2 (was outn)
  float* als2      = alloc((size_t)N);
  float* ald2      = alloc((size_t)N);

  (void)ws_size; (void)n_in;
  hipMemsetAsync(d_ws, 0, zero_bytes, stream);

  const int ebl   = (E + 255) / 256;
  const int nb    = (N + 255) / 256;
  const int nbl4  = (N + 3) / 4;
  const int gemb  = (N + 63) / 64;
  const int sctb  = (E + 1023) / 1024;   // scatter: 4 edges/thread

  // CSR build (by dst)
  k_deg<<<ebl, 256, 0, stream>>>(dstI, deg, E);
  k_chunksum<<<nb, 256, 0, stream>>>(deg, bsum, N);
  k_bscan<<<1, 256, 0, stream>>>(bsum, nb, csr_off, N);
  k_chunkscan<<<nb, 256, 0, stream>>>(deg, bsum, csr_off, fill, N);

  // fused: gemm1 (layer-1 linear + att logits) || scatter + edge dots
  k_gs<<<gemb + sctb, 256, 0, stream>>>(x, W1, as1, ad1, h, als, ald, N, gemb,
                                        dstI, srcI, edge_attr, We1, ae1, We2, ae2,
                                        fill, epk, E);

  // layer-1 aggregation + fused layer-2 linear (out1 never materialized)
  k_agg1<<<nbl4, 256, 0, stream>>>(csr_off, epk, als, ald, h, b1,
                                   W2, as2, ad2, h2buf, als2, ald2, loopdot2, N);

  // layer-2 aggregation (out2 reuses h buffer — h1 dead after agg1)
  k_agg2<<<nbl4, 256, 0, stream>>>(csr_off, epk, als2, ald2, loopdot2, h2buf, b2,
                                   h, N);

  // pool + project
  k_pool<<<((N + 63) / 64 + 3) / 4, 256, 0, stream>>>(h, batch, pooled, cnt, N);
  k_final<<<G, 64, 0, stream>>>(pooled, cnt, Pw, Pb, (float*)d_out);
}

// Round 10
// 239.201 us; speedup vs baseline: 1.0950x; 1.0950x over previous
//
#include <hip/hip_runtime.h>

#define LRELU(a) ((a) > 0.f ? (a) : 0.2f * (a))

// ---------- block-wide inclusive scan helper (256 threads, 4 waves) ----------
__device__ __forceinline__ int blockScanIncl256(int v, int* wl) {
  int t = threadIdx.x, lane = t & 63, w = t >> 6;
  int x = v;
#pragma unroll
  for (int o = 1; o < 64; o <<= 1) {
    int tmp = __shfl_up(x, (unsigned)o, 64);
    if (lane >= o) x += tmp;
  }
  if (lane == 63) wl[w] = x;
  __syncthreads();
  if (t == 0) {
    int s = 0;
#pragma unroll
    for (int j = 0; j < 4; ++j) { int tv = wl[j]; wl[j] = s; s += tv; }
  }
  __syncthreads();
  return x + wl[w];
}

// ---------- CSR build ----------
__global__ __launch_bounds__(256) void k_deg(const int* __restrict__ dst,
                                             int* __restrict__ deg, int E) {
  int e = blockIdx.x * 256 + threadIdx.x;
  if (e < E) atomicAdd(&deg[dst[e]], 1);
}

__global__ __launch_bounds__(256) void k_chunksum(const int* __restrict__ deg,
                                                  int* __restrict__ bsum, int n) {
  __shared__ int wl[4];
  int i = blockIdx.x * 256 + threadIdx.x;
  int v = (i < n) ? deg[i] : 0;
#pragma unroll
  for (int o = 1; o < 64; o <<= 1) v += __shfl_xor(v, o, 64);
  int lane = threadIdx.x & 63, w = threadIdx.x >> 6;
  if (lane == 0) wl[w] = v;
  __syncthreads();
  if (threadIdx.x == 0) bsum[blockIdx.x] = wl[0] + wl[1] + wl[2] + wl[3];
}

// single block; requires nb <= 256 (N <= 65536)
__global__ __launch_bounds__(256) void k_bscan(int* __restrict__ bsum, int nb,
                                               int* __restrict__ csr_off, int n) {
  __shared__ int wl[4];
  int t = threadIdx.x;
  int v = (t < nb) ? bsum[t] : 0;
  int incl = blockScanIncl256(v, wl);
  if (t < nb) bsum[t] = incl - v;  // exclusive block offsets
  if (t == 255) csr_off[n] = incl; // grand total
}

__global__ __launch_bounds__(256) void k_chunkscan(const int* __restrict__ deg,
                                                   const int* __restrict__ bsum,
                                                   int* __restrict__ csr_off,
                                                   int* __restrict__ fill, int n) {
  __shared__ int wl[4];
  int i = blockIdx.x * 256 + threadIdx.x;
  int v = (i < n) ? deg[i] : 0;
  int incl = blockScanIncl256(v, wl);
  int o = bsum[blockIdx.x] + incl - v;
  if (i < n) { csr_off[i] = o; fill[i] = o; }
}

// ---------- chunked-K tiled f32 GEMM body + fused attention-logit epilogue ----
// H[b0:b0+64][0:64] = X[b0:b0+64][0:K] @ W[K][64]; als/ald = h . a per head.
// 256 threads = 16x16, each computes a 4x4 tile. LDS ~17.5KB -> 8 blocks/CU.
template <int K, int HH>
__device__ __forceinline__ void gemm_body(const float* __restrict__ X,
                                          const float* __restrict__ W,
                                          const float* __restrict__ a_s,
                                          const float* __restrict__ a_d,
                                          float* __restrict__ H,
                                          float* __restrict__ als,
                                          float* __restrict__ ald,
                                          int n, int bid) {
  constexpr int KC = 32;
  __shared__ float Xs[64][KC + 4];   // 9216 B
  __shared__ float Ws[KC][64 + 4];   // 8704 B
  int t = threadIdx.x;
  int b0 = bid * 64;
  int tx = t & 15, ty = t >> 4;
  float acc[4][4] = {};
  for (int kc = 0; kc < K; kc += KC) {
    if (kc) __syncthreads();
    {
      int i = t * 8;
      int node = i >> 5, k = i & 31;
      int r = b0 + node;
      float4 v0 = make_float4(0.f, 0.f, 0.f, 0.f), v1 = v0;
      if (r < n) {
        const float* src = X + (size_t)r * K + kc + k;
        v0 = *(const float4*)src;
        v1 = *(const float4*)(src + 4);
      }
      *(float4*)&Xs[node][k] = v0;
      *(float4*)&Xs[node][k + 4] = v1;
    }
    {
      int i = t * 8;
      int kk = i >> 6, c = i & 63;
      const float* src = W + (size_t)(kc + kk) * 64 + c;
      *(float4*)&Ws[kk][c] = *(const float4*)src;
      *(float4*)&Ws[kk][c + 4] = *(const float4*)(src + 4);
    }
    __syncthreads();
#pragma unroll
    for (int k4 = 0; k4 < KC; k4 += 4) {
      float wvf[4][4];
#pragma unroll
      for (int j = 0; j < 4; ++j)
        *(float4*)&wvf[j][0] = *(const float4*)&Ws[k4 + j][tx * 4];
#pragma unroll
      for (int i = 0; i < 4; ++i) {
        float xvf[4];
        *(float4*)&xvf[0] = *(const float4*)&Xs[ty * 4 + i][k4];
#pragma unroll
        for (int kk = 0; kk < 4; ++kk)
#pragma unroll
          for (int j = 0; j < 4; ++j)
            acc[i][j] = fmaf(xvf[kk], wvf[kk][j], acc[i][j]);
      }
    }
  }
#pragma unroll
  for (int i = 0; i < 4; ++i) {
    int node = b0 + ty * 4 + i;
    if (node < n)
      *(float4*)&H[(size_t)node * 64 + tx * 4] =
          make_float4(acc[i][0], acc[i][1], acc[i][2], acc[i][3]);
  }
  // ---- fused attention logits: als/ald[node*HH+head] ----
  constexpr int C = 64 / HH;     // channels per head
  constexpr int GL = C / 4;      // tx lanes per head group
  float asv[4], adv[4];
#pragma unroll
  for (int j = 0; j < 4; ++j) { asv[j] = a_s[tx * 4 + j]; adv[j] = a_d[tx * 4 + j]; }
#pragma unroll
  for (int i = 0; i < 4; ++i) {
    float ps = 0.f, pd = 0.f;
#pragma unroll
    for (int j = 0; j < 4; ++j) {
      ps = fmaf(acc[i][j], asv[j], ps);
      pd = fmaf(acc[i][j], adv[j], pd);
    }
#pragma unroll
    for (int o = 1; o < GL; o <<= 1) {
      ps += __shfl_xor(ps, o, 64);
      pd += __shfl_xor(pd, o, 64);
    }
    int node = b0 + ty * 4 + i;
    if (node < n && (tx & (GL - 1)) == 0) {
      int head = tx / GL;
      als[(size_t)node * HH + head] = ps;
      ald[(size_t)node * HH + head] = pd;
    }
  }
}

__global__ __launch_bounds__(256) void k_gemm2(const float* __restrict__ X,
                                               const float* __restrict__ W,
                                               const float* __restrict__ a_s,
                                               const float* __restrict__ a_d,
                                               float* __restrict__ H,
                                               float* __restrict__ als,
                                               float* __restrict__ ald, int n) {
  gemm_body<64, 1>(X, W, a_s, a_d, H, als, ald, n, blockIdx.x);
}

// ---------- fused: gemm1 (blocks < gemmBlocks) || scatter+edge-dots (the rest) ----
// scatter: edge-ordered coalesced edge_attr read, dots vs (We1@ae1),(We2@ae2),
// ONE 32B scattered struct per edge: epk[p*8] = {d0,d1,d2,d3,q,src,-,-}.
__global__ __launch_bounds__(256) void k_gs(const float* __restrict__ X,
                                            const float* __restrict__ W,
                                            const float* __restrict__ a_s,
                                            const float* __restrict__ a_d,
                                            float* __restrict__ H,
                                            float* __restrict__ als,
                                            float* __restrict__ ald, int n,
                                            int gemmBlocks,
                                            const int* __restrict__ dst,
                                            const int* __restrict__ src,
                                            const float* __restrict__ edge_attr,
                                            const float* __restrict__ We1,
                                            const float* __restrict__ ae1,
                                            const float* __restrict__ We2,
                                            const float* __restrict__ ae2,
                                            int* __restrict__ fill,
                                            float* __restrict__ epk, int E) {
  if ((int)blockIdx.x < gemmBlocks) {
    gemm_body<128, 4>(X, W, a_s, a_d, H, als, ald, n, blockIdx.x);
  } else {
    __shared__ float wa1s[64];  // [k*4+h]
    __shared__ float wa2s[16];
    int t = threadIdx.x;
    if (t < 64) {
      int k = t >> 2, hh = t & 3;
      float s = 0.f;
#pragma unroll
      for (int c = 0; c < 16; ++c)
        s = fmaf(We1[k * 64 + hh * 16 + c], ae1[hh * 16 + c], s);
      wa1s[t] = s;
    } else if (t < 80) {
      int k = t - 64;
      float s = 0.f;
#pragma unroll
      for (int c = 0; c < 64; ++c) s = fmaf(We2[k * 64 + c], ae2[c], s);
      wa2s[k] = s;
    }
    __syncthreads();
    int base = (blockIdx.x - gemmBlocks) * 1024 + t;
#pragma unroll
    for (int r = 0; r < 4; ++r) {
      int e = base + r * 256;
      if (e < E) {
        int d = dst[e], s = src[e];
        const float4* ea = (const float4*)(edge_attr + (size_t)e * 16);
        float ev[16];
        *(float4*)&ev[0]  = ea[0];
        *(float4*)&ev[4]  = ea[1];
        *(float4*)&ev[8]  = ea[2];
        *(float4*)&ev[12] = ea[3];
        float d0 = 0.f, d1 = 0.f, d2 = 0.f, d3 = 0.f, q = 0.f;
#pragma unroll
        for (int k = 0; k < 16; ++k) {
          float4 w1 = *(const float4*)&wa1s[k * 4];
          d0 = fmaf(ev[k], w1.x, d0);
          d1 = fmaf(ev[k], w1.y, d1);
          d2 = fmaf(ev[k], w1.z, d2);
          d3 = fmaf(ev[k], w1.w, d3);
          q  = fmaf(ev[k], wa2s[k], q);
        }
        int p = atomicAdd(&fill[d], 1);
        float* o = epk + (size_t)p * 8;
        *(float4*)o = make_float4(d0, d1, d2, d3);
        *(float4*)(o + 4) = make_float4(q, __int_as_float(s), 0.f, 0.f);
      }
    }
  }
}

// ---------- layer 1 aggregation: SINGLE-PASS batched online softmax ----------
// Batches of 8 edges, double-buffered h gathers; m/den rescaled once per batch
// (identical within each 16-lane head group, no cross-lane reduce needed).
// Σd (per head) and Σq accumulate inline -> self-loop logit + loopdot2.
__global__ __launch_bounds__(256) void k_agg1(const int* __restrict__ csr_off,
                                              const float* __restrict__ epk,
                                              const float* __restrict__ als1,
                                              const float* __restrict__ ald1,
                                              const float* __restrict__ h1,
                                              const float* __restrict__ b1,
                                              float* __restrict__ out1,
                                              float* __restrict__ loopdot2, int n) {
  int t = threadIdx.x, w = t >> 6, lane = t & 63;
  int node = blockIdx.x * 4 + w;
  if (node >= n) return;
  int s0 = csr_off[node], s1 = csr_off[node + 1];
  int nit = s1 - s0;
  int laneH = lane & 3, laneE = lane & 7, laneB8 = (lane >> 2) & 7;
  int head = lane >> 4;
  float adv = ald1[(size_t)node * 4 + laneH];
  float m = -3e38f, den = 0.f, acc = 0.f, sumd = 0.f, sumq = 0.f;
  if (nit > 0) {
    int nb = (nit + 7) >> 3;
    int sv; float dv, qv, ev;
    float bufA[8], bufB[8];
    {
      int i1 = min(s0 + laneE, s1 - 1);
      sv = __float_as_int(epk[(size_t)i1 * 8 + 5]);
      int i2 = min(s0 + laneB8, s1 - 1);
      dv = epk[(size_t)i2 * 8 + laneH];
      qv = epk[(size_t)i2 * 8 + 4];
      int se = __float_as_int(epk[(size_t)i2 * 8 + 5]);
      ev = LRELU(als1[(size_t)se * 4 + laneH] + adv + dv);
    }
#pragma unroll
    for (int j = 0; j < 8; ++j)
      bufA[j] = h1[(size_t)__shfl(sv, j, 64) * 64 + lane];
    for (int b = 0; b < nb; ++b) {
      int svN = 0; float dvN = 0.f, qvN = 0.f, evN = 0.f;
      bool pf = (b + 1 < nb);
      if (pf) {
        int base = s0 + (b + 1) * 8;
        int i1 = min(base + laneE, s1 - 1);
        svN = __float_as_int(epk[(size_t)i1 * 8 + 5]);
        int i2 = min(base + laneB8, s1 - 1);
        dvN = epk[(size_t)i2 * 8 + laneH];
        qvN = epk[(size_t)i2 * 8 + 4];
        int se = __float_as_int(epk[(size_t)i2 * 8 + 5]);
        evN = LRELU(als1[(size_t)se * 4 + laneH] + adv + dvN);
#pragma unroll
        for (int j = 0; j < 8; ++j)
          bufB[j] = h1[(size_t)__shfl(svN, j, 64) * 64 + lane];
      }
      int rem = nit - b * 8;
      // self-loop sums (each (edge,head) counted once: b5==0 lanes)
      if (lane < 32 && laneB8 < rem) {
        sumd += dv;
        if (laneH == 0) sumq += qv;
      }
      // batch logits (per this lane's channel head)
      float a[8];
#pragma unroll
      for (int j = 0; j < 8; ++j)
        a[j] = (j < rem) ? __shfl(ev, j * 4 + head, 64) : -3e38f;
      float bm = fmaxf(fmaxf(fmaxf(a[0], a[1]), fmaxf(a[2], a[3])),
                       fmaxf(fmaxf(a[4], a[5]), fmaxf(a[6], a[7])));
      float nm = fmaxf(m, bm);
      float corr = __expf(m - nm);
      den *= corr;
      acc *= corr;
#pragma unroll
      for (int j = 0; j < 8; ++j) {
        float e = __expf(a[j] - nm);
        den += e;
        acc = fmaf(e, bufA[j], acc);
      }
      m = nm;
      if (pf) {
#pragma unroll
        for (int j = 0; j < 8; ++j) bufA[j] = bufB[j];
        sv = svN; dv = dvN; qv = qvN; ev = evN;
      }
    }
  }
  // reduce self-loop sums across laneB8 (b2..b4) and b5
#pragma unroll
  for (int o = 4; o < 64; o <<= 1) {
    sumd += __shfl_xor(sumd, o, 64);
    sumq += __shfl_xor(sumq, o, 64);
  }
  float cd = fmaxf((float)nit, 1.f);
  float sl = als1[(size_t)node * 4 + laneH] + adv + sumd / cd;
  sl = LRELU(sl);
  if (lane == 0) loopdot2[node] = sumq / cd;
  // merge self-loop term (head's sl lives in lane==head since laneH==head there)
  float sl_ch = __shfl(sl, head, 64);
  float nm = fmaxf(m, sl_ch);
  float corr = __expf(m - nm);
  float es = __expf(sl_ch - nm);
  den = den * corr + es;
  acc = acc * corr + es * h1[(size_t)node * 64 + lane];
  float r = acc / den + b1[lane];
  out1[(size_t)node * 64 + lane] = r > 0.f ? r : expm1f(r);  // ELU fused
}

// ---------- layer 2 aggregation (scalar head): single-pass online softmax ----
__global__ __launch_bounds__(256) void k_agg2(const int* __restrict__ csr_off,
                                              const float* __restrict__ epk,
                                              const float* __restrict__ als2,
                                              const float* __restrict__ ald2,
                                              const float* __restrict__ loopdot2,
                                              const float* __restrict__ h2,
                                              const float* __restrict__ b2,
                                              float* __restrict__ out2, int n) {
  int t = threadIdx.x, w = t >> 6, lane = t & 63;
  int node = blockIdx.x * 4 + w;
  if (node >= n) return;
  int s0 = csr_off[node], s1 = csr_off[node + 1];
  int nit = s1 - s0;
  float adv = ald2[node];
  float m = -3e38f, den = 0.f, acc = 0.f;
  if (nit > 0) {
    int nb = (nit + 7) >> 3;
    int laneE = lane & 7;
    int sv; float ev;
    {
      int i1 = min(s0 + laneE, s1 - 1);
      float2 qs = *(const float2*)(epk + (size_t)i1 * 8 + 4);
      sv = __float_as_int(qs.y);
      ev = LRELU(als2[sv] + adv + qs.x);
    }
    float bufA[8], bufB[8];
#pragma unroll
    for (int j = 0; j < 8; ++j)
      bufA[j] = h2[(size_t)__shfl(sv, j, 64) * 64 + lane];
    for (int b = 0; b < nb; ++b) {
      int svN = 0; float evN = 0.f;
      bool pf = (b + 1 < nb);
      if (pf) {
        int i1 = min(s0 + (b + 1) * 8 + laneE, s1 - 1);
        float2 qs = *(const float2*)(epk + (size_t)i1 * 8 + 4);
        svN = __float_as_int(qs.y);
        evN = LRELU(als2[svN] + adv + qs.x);
#pragma unroll
        for (int j = 0; j < 8; ++j)
          bufB[j] = h2[(size_t)__shfl(svN, j, 64) * 64 + lane];
      }
      int rem = nit - b * 8;
      float a[8];
#pragma unroll
      for (int j = 0; j < 8; ++j)
        a[j] = (j < rem) ? __shfl(ev, j, 64) : -3e38f;
      float bm = fmaxf(fmaxf(fmaxf(a[0], a[1]), fmaxf(a[2], a[3])),
                       fmaxf(fmaxf(a[4], a[5]), fmaxf(a[6], a[7])));
      float nm = fmaxf(m, bm);
      float corr = __expf(m - nm);
      den *= corr;
      acc *= corr;
#pragma unroll
      for (int j = 0; j < 8; ++j) {
        float e = __expf(a[j] - nm);
        den += e;
        acc = fmaf(e, bufA[j], acc);
      }
      m = nm;
      if (pf) {
#pragma unroll
        for (int j = 0; j < 8; ++j) bufA[j] = bufB[j];
        sv = svN; ev = evN;
      }
    }
  }
  // merge self-loop
  float sl = LRELU(als2[node] + adv + loopdot2[node]);
  float nm = fmaxf(m, sl);
  float corr = __expf(m - nm);
  float es = __expf(sl - nm);
  den = den * corr + es;
  acc = acc * corr + es * h2[(size_t)node * 64 + lane];
  out2[(size_t)node * 64 + lane] = acc / den + b2[lane];  // H2=1: mean = identity
}

// ---------- pooling: sorted batch, wave handles 64 consecutive nodes ----------
__global__ __launch_bounds__(256) void k_pool(const float* __restrict__ out2,
                                              const int* __restrict__ batch,
                                              float* __restrict__ pooled,
                                              float* __restrict__ cnt, int n) {
  int wgl = blockIdx.x * 4 + (threadIdx.x >> 6);
  int lane = threadIdx.x & 63;
  int i0 = wgl * 64;
  if (i0 >= n) return;
  int i1 = min(i0 + 64, n);
  int cur = -1;
  float acc = 0.f, c = 0.f;
  for (int i = i0; i < i1; ++i) {
    int g = batch[i];
    if (g != cur) {
      if (cur >= 0) {
        atomicAdd(&pooled[cur * 64 + lane], acc);
        if (lane == 0) atomicAdd(&cnt[cur], c);
      }
      cur = g; acc = 0.f; c = 0.f;
    }
    acc += out2[(size_t)i * 64 + lane];
    c += 1.f;
  }
  if (cur >= 0) {
    atomicAdd(&pooled[cur * 64 + lane], acc);
    if (lane == 0) atomicAdd(&cnt[cur], c);
  }
}

// ---------- final: out[g,:] = (pooled[g,:]/cnt[g]) @ Pw + Pb ----------
__global__ __launch_bounds__(64) void k_final(const float* __restrict__ pooled,
                                              const float* __restrict__ cnt,
                                              const float* __restrict__ Pw,
                                              const float* __restrict__ Pb,
                                              float* __restrict__ out) {
  __shared__ float m[64];
  int g = blockIdx.x, o = threadIdx.x;
  m[o] = pooled[g * 64 + o] / fmaxf(cnt[g], 1.f);
  __syncthreads();
  float s = Pb[o];
#pragma unroll
  for (int c = 0; c < 64; ++c) s = fmaf(m[c], Pw[c * 64 + o], s);
  out[g * 64 + o] = s;
}

extern "C" void kernel_launch(void* const* d_in, const int* in_sizes, int n_in,
                              void* d_out, int out_size, void* d_ws, size_t ws_size,
                              hipStream_t stream) {
  const float* x         = (const float*)d_in[0];
  const int*   edge_index= (const int*)d_in[1];
  const float* edge_attr = (const float*)d_in[2];
  const int*   batch     = (const int*)d_in[3];
  const float* W1  = (const float*)d_in[4];
  const float* as1 = (const float*)d_in[5];
  const float* ad1 = (const float*)d_in[6];
  const float* We1 = (const float*)d_in[7];
  const float* ae1 = (const float*)d_in[8];
  const float* b1  = (const float*)d_in[9];
  const float* W2  = (const float*)d_in[10];
  const float* as2 = (const float*)d_in[11];
  const float* ad2 = (const float*)d_in[12];
  const float* We2 = (const float*)d_in[13];
  const float* ae2 = (const float*)d_in[14];
  const float* b2  = (const float*)d_in[15];
  const float* Pw  = (const float*)d_in[16];
  const float* Pb  = (const float*)d_in[17];

  const int N = in_sizes[0] / 128;
  const int E = in_sizes[1] / 2;
  const int G = out_size / 64;
  const int* srcI = edge_index;
  const int* dstI = edge_index + E;

  // ---- workspace layout (32B-aligned slots) ----
  float* ws = (float*)d_ws;
  size_t off = 0;
  auto alloc = [&](size_t elems) {
    float* p = ws + off;
    off += (elems + 7) & ~(size_t)7;
    return p;
  };
  int*   deg       = (int*)alloc(N);            // zeroed
  float* cnt       = alloc(G);                  // zeroed
  float* pooled    = alloc((size_t)G * 64);     // zeroed
  size_t zero_bytes = off * sizeof(float);
  int*   csr_off   = (int*)alloc(N + 1);
  int*   fill      = (int*)alloc(N);
  int*   bsum      = (int*)alloc(1024);
  float* epk       = alloc((size_t)E * 8);      // {d0,d1,d2,d3,q,src,-,-}/CSR slot
  float* loopdot2  = alloc((size_t)N);
  float* h         = alloc((size_t)N * 64);     // h1; then h2 (gemm2 overwrites)
  float* als       = alloc((size_t)N * 4);      // layer2 reuses first N
  float* ald       = alloc((size_t)N * 4);
  float* outn      = alloc((size_t)N * 64);     // out1; then out2

  (void)ws_size; (void)n_in;
  hipMemsetAsync(d_ws, 0, zero_bytes, stream);

  const int ebl   = (E + 255) / 256;
  const int nb    = (N + 255) / 256;
  const int nbl4  = (N + 3) / 4;
  const int gemb  = (N + 63) / 64;
  const int sctb  = (E + 1023) / 1024;   // scatter: 4 edges/thread

  // CSR build (by dst)
  k_deg<<<ebl, 256, 0, stream>>>(dstI, deg, E);
  k_chunksum<<<nb, 256, 0, stream>>>(deg, bsum, N);
  k_bscan<<<1, 256, 0, stream>>>(bsum, nb, csr_off, N);
  k_chunkscan<<<nb, 256, 0, stream>>>(deg, bsum, csr_off, fill, N);

  // fused: gemm1 (layer-1 linear + att logits) || scatter + edge dots
  k_gs<<<gemb + sctb, 256, 0, stream>>>(x, W1, as1, ad1, h, als, ald, N, gemb,
                                        dstI, srcI, edge_attr, We1, ae1, We2, ae2,
                                        fill, epk, E);

  // layer-1 aggregation (single-pass online softmax; emits loopdot2)
  k_agg1<<<nbl4, 256, 0, stream>>>(csr_off, epk, als, ald, h, b1, outn, loopdot2, N);

  // layer 2 (h2 overwrites h — h1 dead after agg1; als/ald reused as scalars)
  k_gemm2<<<gemb, 256, 0, stream>>>(outn, W2, as2, ad2, h, als, ald, N);
  k_agg2<<<nbl4, 256, 0, stream>>>(csr_off, epk, als, ald, loopdot2, h, b2, outn, N);

  // pool + project
  k_pool<<<((N + 63) / 64 + 3) / 4, 256, 0, stream>>>(outn, batch, pooled, cnt, N);
  k_final<<<G, 64, 0, stream>>>(pooled, cnt, Pw, Pb, (float*)d_out);
}